// Round 2
// baseline (334.722 us; speedup 1.0000x reference)
//
#include <hip/hip_runtime.h>
#include <math.h>

typedef __bf16 bf16;
typedef __bf16 bf16x8 __attribute__((ext_vector_type(8)));
typedef float f32x4 __attribute__((ext_vector_type(4)));
typedef unsigned short u16;
typedef unsigned int u32;

constexpr int BATCH = 32;
constexpr int CH    = 512;   // C
constexpr int CI    = 256;   // C/2
constexpr int NSP   = 1024;  // H*W
constexpr int OCH   = 768;   // 3*CI (theta|phi|g concat)
constexpr float EPSV = 1e-5f;

// async global->LDS, 16B per lane: LDS dest = wave-uniform base + lane*16
__device__ __forceinline__ void gload_lds16(const bf16* g, bf16* l) {
    __builtin_amdgcn_global_load_lds(
        (const __attribute__((address_space(1))) void*)g,
        (__attribute__((address_space(3))) void*)l, 16, 0, 0);
}

// ---------------------------------------------------------------------------
// K0a: weights -> bf16, k-blocked tiles of 64. Also zeroes the BN sums.
// ---------------------------------------------------------------------------
__global__ void prep_weights(const float* __restrict__ Wg, const float* __restrict__ Wt,
                             const float* __restrict__ Wp, const float* __restrict__ Wz,
                             bf16* __restrict__ wc, bf16* __restrict__ wz,
                             float* __restrict__ sums) {
    int tid = blockIdx.x * 256 + threadIdx.x;
    if (tid < 1024) sums[tid] = 0.0f;
    if (tid < OCH * CH) {
        int r = tid / CH, c = tid % CH;
        float v;
        if (r < 256)      v = Wt[r * CH + c];
        else if (r < 512) v = Wp[(r - 256) * CH + c];
        else              v = Wg[(r - 512) * CH + c];
        wc[(size_t)(c >> 6) * (OCH * 64) + r * 64 + (c & 63)] = (bf16)v;
    } else {
        int t2 = tid - OCH * CH;
        if (t2 < CH * CI) {
            int r = t2 / CI, o = t2 % CI;
            wz[(size_t)(o >> 6) * (CH * 64) + r * 64 + (o & 63)] = (bf16)Wz[r * CI + o];
        }
    }
}

// ---------------------------------------------------------------------------
// K0b: x [b][c][n] fp32 -> xb [b][kt][n][64] bf16 (64x64 LDS transpose tiles)
// ---------------------------------------------------------------------------
__global__ void transpose_x(const float* __restrict__ x, bf16* __restrict__ xb) {
    __shared__ bf16 tile[64][64];
    int b = blockIdx.z, kt = blockIdx.y, nb = blockIdx.x;
    int t = threadIdx.x;
    {
        int c_loc = t >> 2;
        int nq = t & 3;
        const float* src = x + ((size_t)b * CH + kt * 64 + c_loc) * NSP + nb * 64 + nq * 16;
        float vv[16];
        *(float4*)(vv + 0)  = *(const float4*)(src + 0);
        *(float4*)(vv + 4)  = *(const float4*)(src + 4);
        *(float4*)(vv + 8)  = *(const float4*)(src + 8);
        *(float4*)(vv + 12) = *(const float4*)(src + 12);
        int nbase = nq * 16;
        #pragma unroll
        for (int i = 0; i < 16; ++i) tile[nbase + i][c_loc] = (bf16)vv[i];
    }
    __syncthreads();
    {
        int n_loc = t >> 2;
        int cq = t & 3;
        bf16* dst = xb + ((((size_t)b * 8 + kt) * NSP) + nb * 64 + n_loc) * 64 + cq * 16;
        *(uint4*)(dst)     = *(const uint4*)&tile[n_loc][cq * 16];
        *(uint4*)(dst + 8) = *(const uint4*)&tile[n_loc][cq * 16 + 8];
    }
}

// ---------------------------------------------------------------------------
// K1: fused projection GEMM.
//   theta -> linear [b][n][ci]; phi/g -> BLOCKED MFMA-fragment tiles
//   (identity copy to LDS => lane-contiguous fragment reads in attention).
// ---------------------------------------------------------------------------
__launch_bounds__(256, 2)
__global__ void proj_gemm(const bf16* __restrict__ xb, const bf16* __restrict__ wc,
                          const float* __restrict__ bt, const float* __restrict__ bp,
                          const float* __restrict__ bg,
                          bf16* __restrict__ theta, bf16* __restrict__ phi_t,
                          bf16* __restrict__ gt_t) {
    constexpr int LDA = 72;
    __shared__ __align__(16) bf16 sm[2 * 128 * LDA];
    bf16* As = sm;
    bf16* Bs = sm + 128 * LDA;
    int b = blockIdx.z;
    int n0 = blockIdx.y * 128;
    int oc0 = blockIdx.x * 128;
    int t = threadIdx.x, lane = t & 63, wid = t >> 6;
    int wm = wid >> 1, wn = wid & 1;
    int l15 = lane & 15, quad = lane >> 4;

    f32x4 acc[4][4] = {};
    for (int kt = 0; kt < 8; ++kt) {
        __syncthreads();
        const bf16* asrc = xb + ((((size_t)b * 8 + kt) * NSP) + n0) * 64;
        const bf16* bsrc = wc + ((size_t)kt * OCH + oc0) * 64;
        for (int s = t; s < 1024; s += 256) {
            int row = s >> 3, c8 = s & 7;
            *(uint4*)&As[row * LDA + c8 * 8] = *(const uint4*)(asrc + (size_t)s * 8);
            *(uint4*)&Bs[row * LDA + c8 * 8] = *(const uint4*)(bsrc + (size_t)s * 8);
        }
        __syncthreads();
        #pragma unroll
        for (int kc = 0; kc < 2; ++kc) {
            bf16x8 af[4], bfv[4];
            #pragma unroll
            for (int i = 0; i < 4; ++i) {
                af[i]  = *(const bf16x8*)&As[(wm * 64 + i * 16 + l15) * LDA + kc * 32 + quad * 8];
                bfv[i] = *(const bf16x8*)&Bs[(wn * 64 + i * 16 + l15) * LDA + kc * 32 + quad * 8];
            }
            #pragma unroll
            for (int i = 0; i < 4; ++i)
                #pragma unroll
                for (int j = 0; j < 4; ++j)
                    acc[i][j] = __builtin_amdgcn_mfma_f32_16x16x32_bf16(af[i], bfv[j], acc[i][j], 0, 0, 0);
        }
    }
    if (oc0 < 256) {
        // theta: linear [b][n][ci]
        #pragma unroll
        for (int j = 0; j < 4; ++j) {
            int och = oc0 + wn * 64 + j * 16 + l15;
            float bv = bt[och];
            #pragma unroll
            for (int i = 0; i < 4; ++i) {
                int nrow = n0 + wm * 64 + i * 16 + quad * 4;
                bf16* p = theta + ((size_t)b * NSP + nrow) * CI + och;
                #pragma unroll
                for (int r = 0; r < 4; ++r)
                    p[(size_t)r * CI] = (bf16)(acc[i][j][r] + bv);
            }
        }
    } else if (oc0 < 512) {
        // phi: blocked K-tiles
        bf16* dstb = phi_t + (size_t)b * 262144;
        #pragma unroll
        for (int j = 0; j < 4; ++j) {
            int och = (oc0 - 256) + wn * 64 + j * 16 + l15;
            float bv = bp[och];
            int kc = och >> 5, qd = (och >> 3) & 3, e = och & 7;
            #pragma unroll
            for (int i = 0; i < 4; ++i) {
                int nrow = n0 + wm * 64 + i * 16 + quad * 4;   // row16 base = quad*4
                int kt = nrow >> 5, h = (nrow >> 4) & 1;
                bf16* p = dstb + (size_t)kt * 8192 +
                          (size_t)(((h * 8 + kc) * 64 + qd * 16 + quad * 4) * 8) + e;
                #pragma unroll
                for (int r = 0; r < 4; ++r)
                    p[r * 8] = (bf16)(acc[i][j][r] + bv);
            }
        }
    } else {
        // g: transpose tile in LDS, then write blocked V-tiles (uint4 = 1 chunk)
        constexpr int LT = 136;
        int obase = oc0 - 512;
        __syncthreads();
        bf16* T = sm;
        #pragma unroll
        for (int j = 0; j < 4; ++j) {
            int och = wn * 64 + j * 16 + l15;
            float bv = bg[obase + och];
            #pragma unroll
            for (int i = 0; i < 4; ++i) {
                int nl = wm * 64 + i * 16 + quad * 4;
                bf16 tmp[4];
                #pragma unroll
                for (int r = 0; r < 4; ++r) tmp[r] = (bf16)(acc[i][j][r] + bv);
                *(uint2*)&T[och * LT + nl] = *(const uint2*)tmp;
            }
        }
        __syncthreads();
        bf16* dstb = gt_t + (size_t)b * 262144;
        for (int s = t; s < 2048; s += 256) {
            int row = s >> 4, part = s & 15;
            int o = obase + row;
            int kglob = n0 + part * 8;
            int kt = kglob >> 5, qd = (kglob >> 3) & 3;
            *(uint4*)(dstb + (size_t)kt * 8192 +
                      (size_t)(((o >> 4) * 64 + qd * 16 + (o & 15)) * 8)) =
                *(const uint4*)&T[row * LT + part * 8];
        }
    }
}

// ---------------------------------------------------------------------------
// K2: fused attention, single-pass online softmax.
// NEW this round (LDS-bandwidth attack):
//   - 32 Q-rows per wave (2 row-groups): each K/V fragment read from LDS
//     now feeds 2 MFMAs -> K/V LDS read traffic per q-row HALVES.
//   - 128 Q-rows per block -> grid 256 = 1 block/CU -> DMA staging per CU
//     halves too. Per-128-q-rows LDS traffic: ~368 KB -> ~208 KB.
//   - K+V double-buffered, stage issued at top of iter, ONE barrier/iter.
//   - s_setprio around MFMA clusters; defer-max rescale (THR=8).
// LDS 75776 B (1 block/CU). VGPR ~270 @ launch_bounds(256,1).
// XCD swizzle: batch b -> XCD b%8 (same-batch KV shares XCD L2).
// ---------------------------------------------------------------------------
__launch_bounds__(256, 1)
__global__ void attn_kernel(const bf16* __restrict__ theta, const bf16* __restrict__ phi_t,
                            const bf16* __restrict__ gt_t, bf16* __restrict__ y) {
    constexpr int LP = 40;
    // layout: K0 @0 (16K) | K1 @16K | V0 @32K | V1 @48K | Pw @64K (10240 B)
    __shared__ __align__(16) char smem[75776];
    bf16* Pw = (bf16*)(smem + 65536);

    int id = blockIdx.x;                 // 256 blocks = 32 b x 8 qt
    int b = (id & 7) + 8 * (id >> 6);    // same batch -> same XCD class
    int qt = (id >> 3) & 7;              // 8 tiles of 128 q-rows

    int t = threadIdx.x, lane = t & 63, w = t >> 6;
    int l15 = lane & 15, quad = lane >> 4;

    // per-wave global source pointers (advance by 8192 elems per tile)
    const bf16* ph_b = phi_t + (size_t)b * 262144 + w * 2048 + lane * 8;
    const bf16* gt_b = gt_t + (size_t)b * 262144 + w * 2048 + lane * 8;

    // Q fragments for 2 row-groups, directly from global (one-time)
    bf16x8 qf[2][8];
    #pragma unroll
    for (int i = 0; i < 2; ++i) {
        const bf16* qrow = theta + ((size_t)b * NSP + qt * 128 + w * 32 + i * 16 + l15) * CI;
        #pragma unroll
        for (int kc = 0; kc < 8; ++kc)
            qf[i][kc] = *(const bf16x8*)(qrow + kc * 32 + quad * 8);
    }

    // preload tile 0 (K -> K0, V -> V0) via async DMA
    {
        bf16* kdst = (bf16*)(smem)         + w * 2048;
        bf16* vdst = (bf16*)(smem + 32768) + w * 2048;
        #pragma unroll
        for (int i = 0; i < 4; ++i) {
            gload_lds16(ph_b + i * 512, kdst + i * 512);
            gload_lds16(gt_b + i * 512, vdst + i * 512);
        }
    }
    __syncthreads();

    f32x4 oacc[2][16] = {};
    float m[2][4]  = {{-1e30f, -1e30f, -1e30f, -1e30f}, {-1e30f, -1e30f, -1e30f, -1e30f}};
    float ps[2][4] = {{0.f, 0.f, 0.f, 0.f}, {0.f, 0.f, 0.f, 0.f}};

    for (int kt = 0; kt < 32; ++kt) {
        int cur = kt & 1;
        bf16* Kc = (bf16*)(smem + (cur << 14));
        bf16* Vc = (bf16*)(smem + 32768 + (cur << 14));

        // (a) async-stage K[kt+1]/V[kt+1] into the other buffers NOW.
        if (kt < 31) {
            const bf16* ksrc = ph_b + (size_t)(kt + 1) * 8192;
            const bf16* vsrc = gt_b + (size_t)(kt + 1) * 8192;
            bf16* kdst = (bf16*)(smem + ((1 - cur) << 14)) + w * 2048;
            bf16* vdst = (bf16*)(smem + 32768 + ((1 - cur) << 14)) + w * 2048;
            #pragma unroll
            for (int i = 0; i < 4; ++i) {
                gload_lds16(ksrc + i * 512, kdst + i * 512);
                gload_lds16(vsrc + i * 512, vdst + i * 512);
            }
        }

        // (b) QK^T: each kf read feeds BOTH row-groups (2x reuse per LDS byte)
        f32x4 s[2][2] = {};
        __builtin_amdgcn_s_setprio(1);
        #pragma unroll
        for (int kc = 0; kc < 8; ++kc) {
            bf16x8 kf0 = *(const bf16x8*)(Kc + kc * 512 + lane * 8);
            bf16x8 kf1 = *(const bf16x8*)(Kc + 4096 + kc * 512 + lane * 8);
            s[0][0] = __builtin_amdgcn_mfma_f32_16x16x32_bf16(qf[0][kc], kf0, s[0][0], 0, 0, 0);
            s[1][0] = __builtin_amdgcn_mfma_f32_16x16x32_bf16(qf[1][kc], kf0, s[1][0], 0, 0, 0);
            s[0][1] = __builtin_amdgcn_mfma_f32_16x16x32_bf16(qf[0][kc], kf1, s[0][1], 0, 0, 0);
            s[1][1] = __builtin_amdgcn_mfma_f32_16x16x32_bf16(qf[1][kc], kf1, s[1][1], 0, 0, 0);
        }
        __builtin_amdgcn_s_setprio(0);

        // (c) online softmax per row-group; defer-max (THR=8)
        float cmx[2][4]; int flag = 0;
        #pragma unroll
        for (int i = 0; i < 2; ++i) {
            #pragma unroll
            for (int r = 0; r < 4; ++r) {
                float c = fmaxf(s[i][0][r], s[i][1][r]);
                c = fmaxf(c, __shfl_xor(c, 1));
                c = fmaxf(c, __shfl_xor(c, 2));
                c = fmaxf(c, __shfl_xor(c, 4));
                c = fmaxf(c, __shfl_xor(c, 8));
                cmx[i][r] = c;
                flag |= (c > m[i][r] + 8.0f) ? 1 : 0;
            }
        }
        if (__any(flag)) {
            #pragma unroll
            for (int i = 0; i < 2; ++i) {
                float alpha[4];
                #pragma unroll
                for (int r = 0; r < 4; ++r) {
                    float mn = fmaxf(m[i][r], cmx[i][r]);
                    alpha[r] = __expf(m[i][r] - mn);
                    m[i][r] = mn;
                    ps[i][r] *= alpha[r];
                }
                #pragma unroll
                for (int nt = 0; nt < 16; ++nt) {
                    oacc[i][nt][0] *= alpha[0];
                    oacc[i][nt][1] *= alpha[1];
                    oacc[i][nt][2] *= alpha[2];
                    oacc[i][nt][3] *= alpha[3];
                }
            }
        }
        #pragma unroll
        for (int i = 0; i < 2; ++i) {
            #pragma unroll
            for (int r = 0; r < 4; ++r) {
                float p0 = __expf(s[i][0][r] - m[i][r]);
                float p1 = __expf(s[i][1][r] - m[i][r]);
                ps[i][r] += p0 + p1;
                Pw[(w * 32 + i * 16 + quad * 4 + r) * LP + l15]      = (bf16)p0;
                Pw[(w * 32 + i * 16 + quad * 4 + r) * LP + 16 + l15] = (bf16)p1;
            }
        }

        // (d) PV: each vf read feeds BOTH row-groups
        bf16x8 pf0 = *(const bf16x8*)&Pw[(w * 32 + l15) * LP + quad * 8];
        bf16x8 pf1 = *(const bf16x8*)&Pw[(w * 32 + 16 + l15) * LP + quad * 8];
        __builtin_amdgcn_s_setprio(1);
        #pragma unroll
        for (int nt = 0; nt < 16; ++nt) {
            bf16x8 vf = *(const bf16x8*)(Vc + nt * 512 + lane * 8);
            oacc[0][nt] = __builtin_amdgcn_mfma_f32_16x16x32_bf16(pf0, vf, oacc[0][nt], 0, 0, 0);
            oacc[1][nt] = __builtin_amdgcn_mfma_f32_16x16x32_bf16(pf1, vf, oacc[1][nt], 0, 0, 0);
        }
        __builtin_amdgcn_s_setprio(0);

        // single barrier per iteration: drains DMA (vmcnt) + makes tiles visible
        __syncthreads();
    }

    #pragma unroll
    for (int i = 0; i < 2; ++i) {
        #pragma unroll
        for (int r = 0; r < 4; ++r) {
            ps[i][r] += __shfl_xor(ps[i][r], 1);
            ps[i][r] += __shfl_xor(ps[i][r], 2);
            ps[i][r] += __shfl_xor(ps[i][r], 4);
            ps[i][r] += __shfl_xor(ps[i][r], 8);
        }
    }

    #pragma unroll
    for (int i = 0; i < 2; ++i) {
        float inv[4];
        #pragma unroll
        for (int r = 0; r < 4; ++r) inv[r] = 1.0f / ps[i][r];
        int nrow = qt * 128 + w * 32 + i * 16 + quad * 4;
        #pragma unroll
        for (int nt = 0; nt < 16; ++nt) {
            int o = nt * 16 + l15;
            bf16* dst = y + ((((size_t)b * 4 + (o >> 6)) * NSP) + nrow) * 64 + (o & 63);
            #pragma unroll
            for (int r = 0; r < 4; ++r)
                dst[(size_t)r * 64] = (bf16)(oacc[i][nt][r] * inv[r]);
        }
    }
}

// ---------------------------------------------------------------------------
// K3: output GEMM + fused BN stats. LDS cross-wave combine -> 128 atomic
// pairs per block. 4 blocks/CU (LDS 38.9 KB, VGPR 72).
// ---------------------------------------------------------------------------
__launch_bounds__(256, 4)
__global__ void out_gemm(const bf16* __restrict__ y, const bf16* __restrict__ wz,
                         const float* __restrict__ bz, float* __restrict__ wy,
                         float* __restrict__ sums) {
    constexpr int LDA = 72;
    __shared__ __align__(16) bf16 As[128 * LDA];
    __shared__ __align__(16) bf16 Bs[128 * LDA];
    __shared__ float redS[128][2], redS2[128][2];
    int b = blockIdx.z;
    int co0 = blockIdx.y * 128;
    int n0 = blockIdx.x * 128;
    int t = threadIdx.x, lane = t & 63, wid = t >> 6;
    int wm = wid >> 1, wn = wid & 1;
    int l15 = lane & 15, quad = lane >> 4;

    f32x4 acc[4][4] = {};
    for (int kt = 0; kt < 4; ++kt) {
        __syncthreads();
        const bf16* asrc = wz + ((size_t)kt * CH + co0) * 64;
        const bf16* bsrc = y + ((((size_t)b * 4 + kt) * NSP) + n0) * 64;
        for (int s = t; s < 1024; s += 256) {
            int row = s >> 3, c8 = s & 7;
            *(uint4*)&As[row * LDA + c8 * 8] = *(const uint4*)(asrc + (size_t)s * 8);
            *(uint4*)&Bs[row * LDA + c8 * 8] = *(const uint4*)(bsrc + (size_t)s * 8);
        }
        __syncthreads();
        #pragma unroll
        for (int kc = 0; kc < 2; ++kc) {
            bf16x8 af[4], bfv[4];
            #pragma unroll
            for (int i = 0; i < 4; ++i) {
                af[i]  = *(const bf16x8*)&As[(wm * 64 + i * 16 + l15) * LDA + kc * 32 + quad * 8];
                bfv[i] = *(const bf16x8*)&Bs[(wn * 64 + i * 16 + l15) * LDA + kc * 32 + quad * 8];
            }
            #pragma unroll
            for (int i = 0; i < 4; ++i)
                #pragma unroll
                for (int j = 0; j < 4; ++j)
                    acc[i][j] = __builtin_amdgcn_mfma_f32_16x16x32_bf16(af[i], bfv[j], acc[i][j], 0, 0, 0);
        }
    }
    #pragma unroll
    for (int i = 0; i < 4; ++i) {
        int cbase = co0 + wm * 64 + i * 16 + quad * 4;
        #pragma unroll
        for (int r = 0; r < 4; ++r) {
            int c = cbase + r;
            float bv = bz[c];
            float s = 0.f, s2 = 0.f;
            #pragma unroll
            for (int jj = 0; jj < 4; ++jj) {
                int n = n0 + wn * 64 + jj * 16 + l15;
                float v = acc[i][jj][r] + bv;
                wy[((size_t)b * CH + c) * NSP + n] = v;
                s += v; s2 += v * v;
            }
            s  += __shfl_xor(s, 1);  s2 += __shfl_xor(s2, 1);
            s  += __shfl_xor(s, 2);  s2 += __shfl_xor(s2, 2);
            s  += __shfl_xor(s, 4);  s2 += __shfl_xor(s2, 4);
            s  += __shfl_xor(s, 8);  s2 += __shfl_xor(s2, 8);
            if (l15 == 0) {
                int cl = wm * 64 + i * 16 + quad * 4 + r;
                redS[cl][wn]  = s;
                redS2[cl][wn] = s2;
            }
        }
    }
    __syncthreads();
    if (t < 128) {
        atomicAdd(&sums[co0 + t],      redS[t][0] + redS[t][1]);
        atomicAdd(&sums[CH + co0 + t], redS2[t][0] + redS2[t][1]);
    }
}

// ---------------------------------------------------------------------------
// K4: BN normalize + affine + residual, in-place on d_out. float4.
// ---------------------------------------------------------------------------
__global__ void bn_finalize(float* __restrict__ out, const float* __restrict__ x,
                            const float* __restrict__ sums,
                            const float* __restrict__ gamma, const float* __restrict__ beta) {
    size_t idx4 = (size_t)blockIdx.x * 256 + threadIdx.x;
    size_t flat = idx4 * 4;
    int ch = (int)((flat >> 10) & 511);
    float S = sums[ch], S2 = sums[CH + ch];
    const float invcnt = 1.0f / (BATCH * NSP);
    float mean = S * invcnt;
    float var = S2 * invcnt - mean * mean;
    float sc = rsqrtf(var + EPSV) * gamma[ch];
    float bi = beta[ch] - mean * sc;
    float4 wv = *(float4*)(out + flat);
    float4 xv = *(const float4*)(x + flat);
    wv.x = wv.x * sc + bi + xv.x;
    wv.y = wv.y * sc + bi + xv.y;
    wv.z = wv.z * sc + bi + xv.z;
    wv.w = wv.w * sc + bi + xv.w;
    *(float4*)(out + flat) = wv;
}

// ---------------------------------------------------------------------------
extern "C" void kernel_launch(void* const* d_in, const int* in_sizes, int n_in,
                              void* d_out, int out_size, void* d_ws, size_t ws_size,
                              hipStream_t stream) {
    const float* x     = (const float*)d_in[0];
    const float* Wg    = (const float*)d_in[1];
    const float* bg    = (const float*)d_in[2];
    const float* Wt    = (const float*)d_in[3];
    const float* bt    = (const float*)d_in[4];
    const float* Wp    = (const float*)d_in[5];
    const float* bp    = (const float*)d_in[6];
    const float* Wz    = (const float*)d_in[7];
    const float* bz    = (const float*)d_in[8];
    const float* gamma = (const float*)d_in[9];
    const float* beta  = (const float*)d_in[10];
    float* out = (float*)d_out;

    char* ws = (char*)d_ws;
    bf16*  y_t   = (bf16*)(ws);                   // [32][4][1024][64]  16,777,216 B
    bf16*  g_t   = (bf16*)(ws + 16777216);        // blocked V tiles   16,777,216 B
    bf16*  wc    = (bf16*)(ws + 33554432);        // [8][768][64]         786,432 B
    bf16*  wzb   = (bf16*)(ws + 34340864);        // [4][512][64]         262,144 B
    float* sums  = (float*)(ws + 34603008);       // [2][512]               4,096 B

    char* ob = (char*)d_out;                      // d_out as scratch until out_gemm
    bf16* xb    = (bf16*)(ob);                    // [32][8][1024][64] 33,554,432 B
    bf16* theta = (bf16*)(ob + 33554432);         // [32][1024][256]   16,777,216 B
    bf16* phi_t = (bf16*)(ob + 50331648);         // blocked K tiles   16,777,216 B

    prep_weights<<<dim3(2048), dim3(256), 0, stream>>>(Wg, Wt, Wp, Wz, wc, wzb, sums);
    transpose_x<<<dim3(16, 8, 32), dim3(256), 0, stream>>>(x, xb);
    proj_gemm<<<dim3(6, 8, 32), dim3(256), 0, stream>>>(xb, wc, bt, bp, bg, theta, phi_t, g_t);
    attn_kernel<<<dim3(256), dim3(256), 0, stream>>>(theta, phi_t, g_t, y_t);
    out_gemm<<<dim3(8, 4, 32), dim3(256), 0, stream>>>(y_t, wzb, bz, out, sums);
    bn_finalize<<<dim3(16384), dim3(256), 0, stream>>>(out, x, sums, gamma, beta);
}

// Round 4
// 289.777 us; speedup vs baseline: 1.1551x; 1.1551x over previous
//
#include <hip/hip_runtime.h>
#include <math.h>

typedef __bf16 bf16;
typedef __bf16 bf16x8 __attribute__((ext_vector_type(8)));
typedef float f32x4 __attribute__((ext_vector_type(4)));
typedef unsigned short u16;
typedef unsigned int u32;

constexpr int BATCH = 32;
constexpr int CH    = 512;   // C
constexpr int CI    = 256;   // C/2
constexpr int NSP   = 1024;  // H*W
constexpr int OCH   = 768;   // 3*CI (theta|phi|g concat)
constexpr float EPSV = 1e-5f;

// async global->LDS, 16B per lane: LDS dest = wave-uniform base + lane*16
__device__ __forceinline__ void gload_lds16(const bf16* g, bf16* l) {
    __builtin_amdgcn_global_load_lds(
        (const __attribute__((address_space(1))) void*)g,
        (__attribute__((address_space(3))) void*)l, 16, 0, 0);
}

__device__ __forceinline__ u32 pack_bf16(float a, float b) {
    union { bf16 h; u16 u; } ca, cb;
    ca.h = (bf16)a; cb.h = (bf16)b;
    return (u32)ca.u | ((u32)cb.u << 16);
}

// ---------------------------------------------------------------------------
// K0a: weights -> bf16, k-blocked tiles of 64. Also zeroes the BN sums.
// ---------------------------------------------------------------------------
__global__ void prep_weights(const float* __restrict__ Wg, const float* __restrict__ Wt,
                             const float* __restrict__ Wp, const float* __restrict__ Wz,
                             bf16* __restrict__ wc, bf16* __restrict__ wz,
                             float* __restrict__ sums) {
    int tid = blockIdx.x * 256 + threadIdx.x;
    if (tid < 1024) sums[tid] = 0.0f;
    if (tid < OCH * CH) {
        int r = tid / CH, c = tid % CH;
        float v;
        if (r < 256)      v = Wt[r * CH + c];
        else if (r < 512) v = Wp[(r - 256) * CH + c];
        else              v = Wg[(r - 512) * CH + c];
        wc[(size_t)(c >> 6) * (OCH * 64) + r * 64 + (c & 63)] = (bf16)v;
    } else {
        int t2 = tid - OCH * CH;
        if (t2 < CH * CI) {
            int r = t2 / CI, o = t2 % CI;
            wz[(size_t)(o >> 6) * (CH * 64) + r * 64 + (o & 63)] = (bf16)Wz[r * CI + o];
        }
    }
}

// ---------------------------------------------------------------------------
// K0b: x [b][c][n] fp32 -> xb [b][kt][n][64] bf16 (64x64 LDS transpose tiles)
// ---------------------------------------------------------------------------
__global__ void transpose_x(const float* __restrict__ x, bf16* __restrict__ xb) {
    __shared__ bf16 tile[64][64];
    int b = blockIdx.z, kt = blockIdx.y, nb = blockIdx.x;
    int t = threadIdx.x;
    {
        int c_loc = t >> 2;
        int nq = t & 3;
        const float* src = x + ((size_t)b * CH + kt * 64 + c_loc) * NSP + nb * 64 + nq * 16;
        float vv[16];
        *(float4*)(vv + 0)  = *(const float4*)(src + 0);
        *(float4*)(vv + 4)  = *(const float4*)(src + 4);
        *(float4*)(vv + 8)  = *(const float4*)(src + 8);
        *(float4*)(vv + 12) = *(const float4*)(src + 12);
        int nbase = nq * 16;
        #pragma unroll
        for (int i = 0; i < 16; ++i) tile[nbase + i][c_loc] = (bf16)vv[i];
    }
    __syncthreads();
    {
        int n_loc = t >> 2;
        int cq = t & 3;
        bf16* dst = xb + ((((size_t)b * 8 + kt) * NSP) + nb * 64 + n_loc) * 64 + cq * 16;
        *(uint4*)(dst)     = *(const uint4*)&tile[n_loc][cq * 16];
        *(uint4*)(dst + 8) = *(const uint4*)&tile[n_loc][cq * 16 + 8];
    }
}

// ---------------------------------------------------------------------------
// K1: fused projection GEMM.
//   theta -> linear [b][n][ci]; phi/g -> BLOCKED MFMA-fragment tiles.
//   R4: V (g) tile kv-order PERMUTED within each 32-kv block so the attention
//   PV A-fragment is lane-local: slot (quad, j) holds
//   kv' = (j<4) ? quad*4+j : 16 + quad*4 + (j-4).
// ---------------------------------------------------------------------------
__launch_bounds__(256, 2)
__global__ void proj_gemm(const bf16* __restrict__ xb, const bf16* __restrict__ wc,
                          const float* __restrict__ bt, const float* __restrict__ bp,
                          const float* __restrict__ bg,
                          bf16* __restrict__ theta, bf16* __restrict__ phi_t,
                          bf16* __restrict__ gt_t) {
    constexpr int LDA = 72;
    __shared__ __align__(16) bf16 sm[2 * 128 * LDA];
    bf16* As = sm;
    bf16* Bs = sm + 128 * LDA;
    int b = blockIdx.z;
    int n0 = blockIdx.y * 128;
    int oc0 = blockIdx.x * 128;
    int t = threadIdx.x, lane = t & 63, wid = t >> 6;
    int wm = wid >> 1, wn = wid & 1;
    int l15 = lane & 15, quad = lane >> 4;

    f32x4 acc[4][4] = {};
    for (int kt = 0; kt < 8; ++kt) {
        __syncthreads();
        const bf16* asrc = xb + ((((size_t)b * 8 + kt) * NSP) + n0) * 64;
        const bf16* bsrc = wc + ((size_t)kt * OCH + oc0) * 64;
        for (int s = t; s < 1024; s += 256) {
            int row = s >> 3, c8 = s & 7;
            *(uint4*)&As[row * LDA + c8 * 8] = *(const uint4*)(asrc + (size_t)s * 8);
            *(uint4*)&Bs[row * LDA + c8 * 8] = *(const uint4*)(bsrc + (size_t)s * 8);
        }
        __syncthreads();
        #pragma unroll
        for (int kc = 0; kc < 2; ++kc) {
            bf16x8 af[4], bfv[4];
            #pragma unroll
            for (int i = 0; i < 4; ++i) {
                af[i]  = *(const bf16x8*)&As[(wm * 64 + i * 16 + l15) * LDA + kc * 32 + quad * 8];
                bfv[i] = *(const bf16x8*)&Bs[(wn * 64 + i * 16 + l15) * LDA + kc * 32 + quad * 8];
            }
            #pragma unroll
            for (int i = 0; i < 4; ++i)
                #pragma unroll
                for (int j = 0; j < 4; ++j)
                    acc[i][j] = __builtin_amdgcn_mfma_f32_16x16x32_bf16(af[i], bfv[j], acc[i][j], 0, 0, 0);
        }
    }
    if (oc0 < 256) {
        // theta: linear [b][n][ci]
        #pragma unroll
        for (int j = 0; j < 4; ++j) {
            int och = oc0 + wn * 64 + j * 16 + l15;
            float bv = bt[och];
            #pragma unroll
            for (int i = 0; i < 4; ++i) {
                int nrow = n0 + wm * 64 + i * 16 + quad * 4;
                bf16* p = theta + ((size_t)b * NSP + nrow) * CI + och;
                #pragma unroll
                for (int r = 0; r < 4; ++r)
                    p[(size_t)r * CI] = (bf16)(acc[i][j][r] + bv);
            }
        }
    } else if (oc0 < 512) {
        // phi: blocked K-tiles
        bf16* dstb = phi_t + (size_t)b * 262144;
        #pragma unroll
        for (int j = 0; j < 4; ++j) {
            int och = (oc0 - 256) + wn * 64 + j * 16 + l15;
            float bv = bp[och];
            int kc = och >> 5, qd = (och >> 3) & 3, e = och & 7;
            #pragma unroll
            for (int i = 0; i < 4; ++i) {
                int nrow = n0 + wm * 64 + i * 16 + quad * 4;   // row16 base = quad*4
                int kt = nrow >> 5, h = (nrow >> 4) & 1;
                bf16* p = dstb + (size_t)kt * 8192 +
                          (size_t)(((h * 8 + kc) * 64 + qd * 16 + quad * 4) * 8) + e;
                #pragma unroll
                for (int r = 0; r < 4; ++r)
                    p[r * 8] = (bf16)(acc[i][j][r] + bv);
            }
        }
    } else {
        // g: transpose tile in LDS, then write PERMUTED blocked V-tiles.
        // kv = qd*8 + jj (jj=0..7) goes to slot (quad', j') with
        // quad' = (2*qd + (jj>>2)) & 3, j' = (qd&2)*2 + (jj&3)
        // -> two uint2 writes per (o, qd) chunk.
        constexpr int LT = 136;
        int obase = oc0 - 512;
        __syncthreads();
        bf16* T = sm;
        #pragma unroll
        for (int j = 0; j < 4; ++j) {
            int och = wn * 64 + j * 16 + l15;
            float bv = bg[obase + och];
            #pragma unroll
            for (int i = 0; i < 4; ++i) {
                int nl = wm * 64 + i * 16 + quad * 4;
                bf16 tmp[4];
                #pragma unroll
                for (int r = 0; r < 4; ++r) tmp[r] = (bf16)(acc[i][j][r] + bv);
                *(uint2*)&T[och * LT + nl] = *(const uint2*)tmp;
            }
        }
        __syncthreads();
        bf16* dstb = gt_t + (size_t)b * 262144;
        for (int s = t; s < 2048; s += 256) {
            int row = s >> 4, part = s & 15;
            int o = obase + row;
            int kglob = n0 + part * 8;
            int kt = kglob >> 5, qd = (kglob >> 3) & 3;
            int qa = (2 * qd) & 3, qb = (2 * qd + 1) & 3;
            int jb = (qd & 2) * 2;             // 0 or 4
            bf16* base = dstb + (size_t)kt * 8192 + (size_t)((o >> 4) * 512 + (o & 15) * 8);
            *(uint2*)(base + qa * 128 + jb) = *(const uint2*)&T[row * LT + part * 8];
            *(uint2*)(base + qb * 128 + jb) = *(const uint2*)&T[row * LT + part * 8 + 4];
        }
    }
}

// ---------------------------------------------------------------------------
// K2: fused attention, single-pass online softmax.
// R4: R1 skeleton (512 blocks, 2/CU, K+V dbuf, 1 barrier/iter) + swapped
// QK^T (S^T = mfma(K,Q)) with FULLY lane-local softmax AND lane-local PV
// A-fragment (V tile kv-permuted at production):
//   - lane (q=l15, quad) holds S for kv = quad*4+r (s0) and 16+quad*4+r (s1)
//   - row-max: 7 in-lane fmax + 2 shfl_xor (16, 32)
//   - P-fragment = own 8 exponentials packed: ZERO cross-lane repack,
//     no LDS P roundtrip (the R3 bug — source-lane-evaluated select — is
//     structurally eliminated).
//   - m, ps per-lane scalars; defer-max THR=8; alpha/inv redistributed with
//     4 shuffles (sources = lanes 0..15, which hold q=quad*4+r; all quads
//     agree on m after the max combine).
// LDS 65536 B -> 2 blocks/CU. XCD swizzle: batch b -> XCD b%8.
// ---------------------------------------------------------------------------
__launch_bounds__(256, 2)
__global__ void attn_kernel(const bf16* __restrict__ theta, const bf16* __restrict__ phi_t,
                            const bf16* __restrict__ gt_t, bf16* __restrict__ y) {
    // layout: K0 @0 (16K) | K1 @16K | V0 @32K | V1 @48K
    __shared__ __align__(16) char smem[65536];

    int id = blockIdx.x;
    int j = id >> 3;
    int qt = j & 15;
    int b = (id & 7) + 8 * (j >> 4);

    int t = threadIdx.x, lane = t & 63, w = t >> 6;
    int l15 = lane & 15, quad = lane >> 4;

    // per-wave global source pointers (advance by 8192 elems per tile)
    const bf16* ph_b = phi_t + (size_t)b * 262144 + w * 2048 + lane * 8;
    const bf16* gt_b = gt_t + (size_t)b * 262144 + w * 2048 + lane * 8;

    // Q fragments directly from global (one-time); lane->q, quad->d-chunk
    bf16x8 qf[8];
    {
        const bf16* qrow = theta + ((size_t)b * NSP + qt * 64 + w * 16 + l15) * CI;
        #pragma unroll
        for (int kc = 0; kc < 8; ++kc)
            qf[kc] = *(const bf16x8*)(qrow + kc * 32 + quad * 8);
    }

    // preload tile 0 (K -> K0, V -> V0) via async DMA
    {
        bf16* kdst = (bf16*)(smem)         + w * 2048;
        bf16* vdst = (bf16*)(smem + 32768) + w * 2048;
        #pragma unroll
        for (int i = 0; i < 4; ++i) {
            gload_lds16(ph_b + i * 512, kdst + i * 512);
            gload_lds16(gt_b + i * 512, vdst + i * 512);
        }
    }
    __syncthreads();

    f32x4 oacc[16] = {};
    float m = -1e30f;   // running max for q = l15 (per-lane)
    float ps = 0.0f;    // partial softmax denom for q = l15 (this quad's kv)

    for (int kt = 0; kt < 32; ++kt) {
        int cur = kt & 1;
        bf16* Kc = (bf16*)(smem + (cur << 14));
        bf16* Vc = (bf16*)(smem + 32768 + (cur << 14));

        // (a) async-stage K[kt+1]/V[kt+1] into the other buffers NOW.
        if (kt < 31) {
            const bf16* ksrc = ph_b + (size_t)(kt + 1) * 8192;
            const bf16* vsrc = gt_b + (size_t)(kt + 1) * 8192;
            bf16* kdst = (bf16*)(smem + ((1 - cur) << 14)) + w * 2048;
            bf16* vdst = (bf16*)(smem + 32768 + ((1 - cur) << 14)) + w * 2048;
            #pragma unroll
            for (int i = 0; i < 4; ++i) {
                gload_lds16(ksrc + i * 512, kdst + i * 512);
                gload_lds16(vsrc + i * 512, vdst + i * 512);
            }
        }

        // (b) swapped QK^T: S^T = K * Q^T. Lane holds kv=quad*4+r (s0: kv<16,
        //     s1: kv>=16) for q = l15.
        f32x4 s0 = {}, s1 = {};
        __builtin_amdgcn_s_setprio(1);
        #pragma unroll
        for (int kc = 0; kc < 8; ++kc) {
            bf16x8 kf0 = *(const bf16x8*)(Kc + kc * 512 + lane * 8);
            bf16x8 kf1 = *(const bf16x8*)(Kc + 4096 + kc * 512 + lane * 8);
            s0 = __builtin_amdgcn_mfma_f32_16x16x32_bf16(kf0, qf[kc], s0, 0, 0, 0);
            s1 = __builtin_amdgcn_mfma_f32_16x16x32_bf16(kf1, qf[kc], s1, 0, 0, 0);
        }
        __builtin_amdgcn_s_setprio(0);

        // (c) in-register online softmax (per-lane q-row)
        float c = fmaxf(fmaxf(fmaxf(s0[0], s0[1]), fmaxf(s0[2], s0[3])),
                        fmaxf(fmaxf(s1[0], s1[1]), fmaxf(s1[2], s1[3])));
        c = fmaxf(c, __shfl_xor(c, 16));
        c = fmaxf(c, __shfl_xor(c, 32));
        int flag = (c > m + 8.0f) ? 1 : 0;
        if (__any(flag)) {
            float mn = fmaxf(m, c);
            float alpha = __expf(m - mn);
            m = mn;
            ps *= alpha;
            float a0 = __shfl(alpha, quad * 4 + 0);
            float a1 = __shfl(alpha, quad * 4 + 1);
            float a2 = __shfl(alpha, quad * 4 + 2);
            float a3 = __shfl(alpha, quad * 4 + 3);
            #pragma unroll
            for (int nt = 0; nt < 16; ++nt) {
                oacc[nt][0] *= a0;
                oacc[nt][1] *= a1;
                oacc[nt][2] *= a2;
                oacc[nt][3] *= a3;
            }
        }
        float p0 = __expf(s0[0] - m), p1 = __expf(s0[1] - m);
        float p2 = __expf(s0[2] - m), p3 = __expf(s0[3] - m);
        float p4 = __expf(s1[0] - m), p5 = __expf(s1[1] - m);
        float p6 = __expf(s1[2] - m), p7 = __expf(s1[3] - m);
        ps += ((p0 + p1) + (p2 + p3)) + ((p4 + p5) + (p6 + p7));

        // PV A-fragment is LANE-LOCAL thanks to the permuted V tile:
        // pf[j] = P[q][kv' = j<4 ? quad*4+j : 16+quad*4+(j-4)] = own p[j].
        bf16x8 pf;
        {
            union { u32 u[4]; bf16x8 v; } cvt;
            cvt.u[0] = pack_bf16(p0, p1);
            cvt.u[1] = pack_bf16(p2, p3);
            cvt.u[2] = pack_bf16(p4, p5);
            cvt.u[3] = pack_bf16(p6, p7);
            pf = cvt.v;
        }

        // (d) PV from Vc (kv-permuted tile matches pf layout)
        __builtin_amdgcn_s_setprio(1);
        #pragma unroll
        for (int nt = 0; nt < 16; ++nt) {
            bf16x8 vf = *(const bf16x8*)(Vc + nt * 512 + lane * 8);
            oacc[nt] = __builtin_amdgcn_mfma_f32_16x16x32_bf16(pf, vf, oacc[nt], 0, 0, 0);
        }
        __builtin_amdgcn_s_setprio(0);

        // single barrier per iteration: drains DMA (vmcnt) + makes tiles visible
        __syncthreads();
    }

    // final denom: combine the 4 quad-partials for each q, then redistribute
    ps += __shfl_xor(ps, 16);
    ps += __shfl_xor(ps, 32);
    float inv = 1.0f / ps;
    float inv0 = __shfl(inv, quad * 4 + 0);
    float inv1 = __shfl(inv, quad * 4 + 1);
    float inv2 = __shfl(inv, quad * 4 + 2);
    float inv3 = __shfl(inv, quad * 4 + 3);

    int nrow = qt * 64 + w * 16 + quad * 4;
    #pragma unroll
    for (int nt = 0; nt < 16; ++nt) {
        int o = nt * 16 + l15;
        bf16* dst = y + ((((size_t)b * 4 + (o >> 6)) * NSP) + nrow) * 64 + (o & 63);
        dst[0]           = (bf16)(oacc[nt][0] * inv0);
        dst[(size_t)64]  = (bf16)(oacc[nt][1] * inv1);
        dst[(size_t)128] = (bf16)(oacc[nt][2] * inv2);
        dst[(size_t)192] = (bf16)(oacc[nt][3] * inv3);
    }
}

// ---------------------------------------------------------------------------
// K3: output GEMM + fused BN stats. LDS cross-wave combine -> 128 atomic
// pairs per block. 4 blocks/CU (LDS 38.9 KB, VGPR 72).
// ---------------------------------------------------------------------------
__launch_bounds__(256, 4)
__global__ void out_gemm(const bf16* __restrict__ y, const bf16* __restrict__ wz,
                         const float* __restrict__ bz, float* __restrict__ wy,
                         float* __restrict__ sums) {
    constexpr int LDA = 72;
    __shared__ __align__(16) bf16 As[128 * LDA];
    __shared__ __align__(16) bf16 Bs[128 * LDA];
    __shared__ float redS[128][2], redS2[128][2];
    int b = blockIdx.z;
    int co0 = blockIdx.y * 128;
    int n0 = blockIdx.x * 128;
    int t = threadIdx.x, lane = t & 63, wid = t >> 6;
    int wm = wid >> 1, wn = wid & 1;
    int l15 = lane & 15, quad = lane >> 4;

    f32x4 acc[4][4] = {};
    for (int kt = 0; kt < 4; ++kt) {
        __syncthreads();
        const bf16* asrc = wz + ((size_t)kt * CH + co0) * 64;
        const bf16* bsrc = y + ((((size_t)b * 4 + kt) * NSP) + n0) * 64;
        for (int s = t; s < 1024; s += 256) {
            int row = s >> 3, c8 = s & 7;
            *(uint4*)&As[row * LDA + c8 * 8] = *(const uint4*)(asrc + (size_t)s * 8);
            *(uint4*)&Bs[row * LDA + c8 * 8] = *(const uint4*)(bsrc + (size_t)s * 8);
        }
        __syncthreads();
        #pragma unroll
        for (int kc = 0; kc < 2; ++kc) {
            bf16x8 af[4], bfv[4];
            #pragma unroll
            for (int i = 0; i < 4; ++i) {
                af[i]  = *(const bf16x8*)&As[(wm * 64 + i * 16 + l15) * LDA + kc * 32 + quad * 8];
                bfv[i] = *(const bf16x8*)&Bs[(wn * 64 + i * 16 + l15) * LDA + kc * 32 + quad * 8];
            }
            #pragma unroll
            for (int i = 0; i < 4; ++i)
                #pragma unroll
                for (int j = 0; j < 4; ++j)
                    acc[i][j] = __builtin_amdgcn_mfma_f32_16x16x32_bf16(af[i], bfv[j], acc[i][j], 0, 0, 0);
        }
    }
    #pragma unroll
    for (int i = 0; i < 4; ++i) {
        int cbase = co0 + wm * 64 + i * 16 + quad * 4;
        #pragma unroll
        for (int r = 0; r < 4; ++r) {
            int c = cbase + r;
            float bv = bz[c];
            float s = 0.f, s2 = 0.f;
            #pragma unroll
            for (int jj = 0; jj < 4; ++jj) {
                int n = n0 + wn * 64 + jj * 16 + l15;
                float v = acc[i][jj][r] + bv;
                wy[((size_t)b * CH + c) * NSP + n] = v;
                s += v; s2 += v * v;
            }
            s  += __shfl_xor(s, 1);  s2 += __shfl_xor(s2, 1);
            s  += __shfl_xor(s, 2);  s2 += __shfl_xor(s2, 2);
            s  += __shfl_xor(s, 4);  s2 += __shfl_xor(s2, 4);
            s  += __shfl_xor(s, 8);  s2 += __shfl_xor(s2, 8);
            if (l15 == 0) {
                int cl = wm * 64 + i * 16 + quad * 4 + r;
                redS[cl][wn]  = s;
                redS2[cl][wn] = s2;
            }
        }
    }
    __syncthreads();
    if (t < 128) {
        atomicAdd(&sums[co0 + t],      redS[t][0] + redS[t][1]);
        atomicAdd(&sums[CH + co0 + t], redS2[t][0] + redS2[t][1]);
    }
}

// ---------------------------------------------------------------------------
// K4: BN normalize + affine + residual, in-place on d_out. float4.
// ---------------------------------------------------------------------------
__global__ void bn_finalize(float* __restrict__ out, const float* __restrict__ x,
                            const float* __restrict__ sums,
                            const float* __restrict__ gamma, const float* __restrict__ beta) {
    size_t idx4 = (size_t)blockIdx.x * 256 + threadIdx.x;
    size_t flat = idx4 * 4;
    int ch = (int)((flat >> 10) & 511);
    float S = sums[ch], S2 = sums[CH + ch];
    const float invcnt = 1.0f / (BATCH * NSP);
    float mean = S * invcnt;
    float var = S2 * invcnt - mean * mean;
    float sc = rsqrtf(var + EPSV) * gamma[ch];
    float bi = beta[ch] - mean * sc;
    float4 wv = *(float4*)(out + flat);
    float4 xv = *(const float4*)(x + flat);
    wv.x = wv.x * sc + bi + xv.x;
    wv.y = wv.y * sc + bi + xv.y;
    wv.z = wv.z * sc + bi + xv.z;
    wv.w = wv.w * sc + bi + xv.w;
    *(float4*)(out + flat) = wv;
}

// ---------------------------------------------------------------------------
extern "C" void kernel_launch(void* const* d_in, const int* in_sizes, int n_in,
                              void* d_out, int out_size, void* d_ws, size_t ws_size,
                              hipStream_t stream) {
    const float* x     = (const float*)d_in[0];
    const float* Wg    = (const float*)d_in[1];
    const float* bg    = (const float*)d_in[2];
    const float* Wt    = (const float*)d_in[3];
    const float* bt    = (const float*)d_in[4];
    const float* Wp    = (const float*)d_in[5];
    const float* bp    = (const float*)d_in[6];
    const float* Wz    = (const float*)d_in[7];
    const float* bz    = (const float*)d_in[8];
    const float* gamma = (const float*)d_in[9];
    const float* beta  = (const float*)d_in[10];
    float* out = (float*)d_out;

    char* ws = (char*)d_ws;
    bf16*  y_t   = (bf16*)(ws);                   // [32][4][1024][64]  16,777,216 B
    bf16*  g_t   = (bf16*)(ws + 16777216);        // blocked V tiles   16,777,216 B
    bf16*  wc    = (bf16*)(ws + 33554432);        // [8][768][64]         786,432 B
    bf16*  wzb   = (bf16*)(ws + 34340864);        // [4][512][64]         262,144 B
    float* sums  = (float*)(ws + 34603008);       // [2][512]               4,096 B

    char* ob = (char*)d_out;                      // d_out as scratch until out_gemm
    bf16* xb    = (bf16*)(ob);                    // [32][8][1024][64] 33,554,432 B
    bf16* theta = (bf16*)(ob + 33554432);         // [32][1024][256]   16,777,216 B
    bf16* phi_t = (bf16*)(ob + 50331648);         // blocked K tiles   16,777,216 B

    prep_weights<<<dim3(2048), dim3(256), 0, stream>>>(Wg, Wt, Wp, Wz, wc, wzb, sums);
    transpose_x<<<dim3(16, 8, 32), dim3(256), 0, stream>>>(x, xb);
    proj_gemm<<<dim3(6, 8, 32), dim3(256), 0, stream>>>(xb, wc, bt, bp, bg, theta, phi_t, g_t);
    attn_kernel<<<dim3(512), dim3(256), 0, stream>>>(theta, phi_t, g_t, y_t);
    out_gemm<<<dim3(8, 4, 32), dim3(256), 0, stream>>>(y_t, wzb, bz, out, sums);
    bn_finalize<<<dim3(16384), dim3(256), 0, stream>>>(out, x, sums, gamma, beta);
}

// Round 5
// 285.396 us; speedup vs baseline: 1.1728x; 1.0154x over previous
//
#include <hip/hip_runtime.h>
#include <math.h>

typedef __bf16 bf16;
typedef __bf16 bf16x8 __attribute__((ext_vector_type(8)));
typedef float f32x4 __attribute__((ext_vector_type(4)));
typedef unsigned short u16;
typedef unsigned int u32;

constexpr int BATCH = 32;
constexpr int CH    = 512;   // C
constexpr int CI    = 256;   // C/2
constexpr int NSP   = 1024;  // H*W
constexpr int OCH   = 768;   // 3*CI (theta|phi|g concat)
constexpr float EPSV = 1e-5f;

// async global->LDS, 16B per lane: LDS dest = wave-uniform base + lane*16
__device__ __forceinline__ void gload_lds16(const bf16* g, bf16* l) {
    __builtin_amdgcn_global_load_lds(
        (const __attribute__((address_space(1))) void*)g,
        (__attribute__((address_space(3))) void*)l, 16, 0, 0);
}

__device__ __forceinline__ u32 pack_bf16(float a, float b) {
    union { bf16 h; u16 u; } ca, cb;
    ca.h = (bf16)a; cb.h = (bf16)b;
    return (u32)ca.u | ((u32)cb.u << 16);
}

// ---------------------------------------------------------------------------
// K0a: weights -> bf16, k-blocked tiles of 64. Also zeroes the BN sums.
// ---------------------------------------------------------------------------
__global__ void prep_weights(const float* __restrict__ Wg, const float* __restrict__ Wt,
                             const float* __restrict__ Wp, const float* __restrict__ Wz,
                             bf16* __restrict__ wc, bf16* __restrict__ wz,
                             float* __restrict__ sums) {
    int tid = blockIdx.x * 256 + threadIdx.x;
    if (tid < 1024) sums[tid] = 0.0f;
    if (tid < OCH * CH) {
        int r = tid / CH, c = tid % CH;
        float v;
        if (r < 256)      v = Wt[r * CH + c];
        else if (r < 512) v = Wp[(r - 256) * CH + c];
        else              v = Wg[(r - 512) * CH + c];
        wc[(size_t)(c >> 6) * (OCH * 64) + r * 64 + (c & 63)] = (bf16)v;
    } else {
        int t2 = tid - OCH * CH;
        if (t2 < CH * CI) {
            int r = t2 / CI, o = t2 % CI;
            wz[(size_t)(o >> 6) * (CH * 64) + r * 64 + (o & 63)] = (bf16)Wz[r * CI + o];
        }
    }
}

// ---------------------------------------------------------------------------
// K0b: x [b][c][n] fp32 -> xb [b][kt][n][64] bf16 (64x64 LDS transpose tiles)
// ---------------------------------------------------------------------------
__global__ void transpose_x(const float* __restrict__ x, bf16* __restrict__ xb) {
    __shared__ bf16 tile[64][64];
    int b = blockIdx.z, kt = blockIdx.y, nb = blockIdx.x;
    int t = threadIdx.x;
    {
        int c_loc = t >> 2;
        int nq = t & 3;
        const float* src = x + ((size_t)b * CH + kt * 64 + c_loc) * NSP + nb * 64 + nq * 16;
        float vv[16];
        *(float4*)(vv + 0)  = *(const float4*)(src + 0);
        *(float4*)(vv + 4)  = *(const float4*)(src + 4);
        *(float4*)(vv + 8)  = *(const float4*)(src + 8);
        *(float4*)(vv + 12) = *(const float4*)(src + 12);
        int nbase = nq * 16;
        #pragma unroll
        for (int i = 0; i < 16; ++i) tile[nbase + i][c_loc] = (bf16)vv[i];
    }
    __syncthreads();
    {
        int n_loc = t >> 2;
        int cq = t & 3;
        bf16* dst = xb + ((((size_t)b * 8 + kt) * NSP) + nb * 64 + n_loc) * 64 + cq * 16;
        *(uint4*)(dst)     = *(const uint4*)&tile[n_loc][cq * 16];
        *(uint4*)(dst + 8) = *(const uint4*)&tile[n_loc][cq * 16 + 8];
    }
}

// ---------------------------------------------------------------------------
// K1: fused projection GEMM.
//   theta -> linear [b][n][ci]; phi/g -> BLOCKED MFMA-fragment tiles.
//   V (g) tile kv-order PERMUTED within each 32-kv block so the attention
//   PV A-fragment is lane-local (see R4).
// ---------------------------------------------------------------------------
__launch_bounds__(256, 2)
__global__ void proj_gemm(const bf16* __restrict__ xb, const bf16* __restrict__ wc,
                          const float* __restrict__ bt, const float* __restrict__ bp,
                          const float* __restrict__ bg,
                          bf16* __restrict__ theta, bf16* __restrict__ phi_t,
                          bf16* __restrict__ gt_t) {
    constexpr int LDA = 72;
    __shared__ __align__(16) bf16 sm[2 * 128 * LDA];
    bf16* As = sm;
    bf16* Bs = sm + 128 * LDA;
    int b = blockIdx.z;
    int n0 = blockIdx.y * 128;
    int oc0 = blockIdx.x * 128;
    int t = threadIdx.x, lane = t & 63, wid = t >> 6;
    int wm = wid >> 1, wn = wid & 1;
    int l15 = lane & 15, quad = lane >> 4;

    f32x4 acc[4][4] = {};
    for (int kt = 0; kt < 8; ++kt) {
        __syncthreads();
        const bf16* asrc = xb + ((((size_t)b * 8 + kt) * NSP) + n0) * 64;
        const bf16* bsrc = wc + ((size_t)kt * OCH + oc0) * 64;
        for (int s = t; s < 1024; s += 256) {
            int row = s >> 3, c8 = s & 7;
            *(uint4*)&As[row * LDA + c8 * 8] = *(const uint4*)(asrc + (size_t)s * 8);
            *(uint4*)&Bs[row * LDA + c8 * 8] = *(const uint4*)(bsrc + (size_t)s * 8);
        }
        __syncthreads();
        #pragma unroll
        for (int kc = 0; kc < 2; ++kc) {
            bf16x8 af[4], bfv[4];
            #pragma unroll
            for (int i = 0; i < 4; ++i) {
                af[i]  = *(const bf16x8*)&As[(wm * 64 + i * 16 + l15) * LDA + kc * 32 + quad * 8];
                bfv[i] = *(const bf16x8*)&Bs[(wn * 64 + i * 16 + l15) * LDA + kc * 32 + quad * 8];
            }
            #pragma unroll
            for (int i = 0; i < 4; ++i)
                #pragma unroll
                for (int j = 0; j < 4; ++j)
                    acc[i][j] = __builtin_amdgcn_mfma_f32_16x16x32_bf16(af[i], bfv[j], acc[i][j], 0, 0, 0);
        }
    }
    if (oc0 < 256) {
        // theta: linear [b][n][ci]
        #pragma unroll
        for (int j = 0; j < 4; ++j) {
            int och = oc0 + wn * 64 + j * 16 + l15;
            float bv = bt[och];
            #pragma unroll
            for (int i = 0; i < 4; ++i) {
                int nrow = n0 + wm * 64 + i * 16 + quad * 4;
                bf16* p = theta + ((size_t)b * NSP + nrow) * CI + och;
                #pragma unroll
                for (int r = 0; r < 4; ++r)
                    p[(size_t)r * CI] = (bf16)(acc[i][j][r] + bv);
            }
        }
    } else if (oc0 < 512) {
        // phi: blocked K-tiles
        bf16* dstb = phi_t + (size_t)b * 262144;
        #pragma unroll
        for (int j = 0; j < 4; ++j) {
            int och = (oc0 - 256) + wn * 64 + j * 16 + l15;
            float bv = bp[och];
            int kc = och >> 5, qd = (och >> 3) & 3, e = och & 7;
            #pragma unroll
            for (int i = 0; i < 4; ++i) {
                int nrow = n0 + wm * 64 + i * 16 + quad * 4;   // row16 base = quad*4
                int kt = nrow >> 5, h = (nrow >> 4) & 1;
                bf16* p = dstb + (size_t)kt * 8192 +
                          (size_t)(((h * 8 + kc) * 64 + qd * 16 + quad * 4) * 8) + e;
                #pragma unroll
                for (int r = 0; r < 4; ++r)
                    p[r * 8] = (bf16)(acc[i][j][r] + bv);
            }
        }
    } else {
        // g: transpose tile in LDS, then write PERMUTED blocked V-tiles.
        constexpr int LT = 136;
        int obase = oc0 - 512;
        __syncthreads();
        bf16* T = sm;
        #pragma unroll
        for (int j = 0; j < 4; ++j) {
            int och = wn * 64 + j * 16 + l15;
            float bv = bg[obase + och];
            #pragma unroll
            for (int i = 0; i < 4; ++i) {
                int nl = wm * 64 + i * 16 + quad * 4;
                bf16 tmp[4];
                #pragma unroll
                for (int r = 0; r < 4; ++r) tmp[r] = (bf16)(acc[i][j][r] + bv);
                *(uint2*)&T[och * LT + nl] = *(const uint2*)tmp;
            }
        }
        __syncthreads();
        bf16* dstb = gt_t + (size_t)b * 262144;
        for (int s = t; s < 2048; s += 256) {
            int row = s >> 4, part = s & 15;
            int o = obase + row;
            int kglob = n0 + part * 8;
            int kt = kglob >> 5, qd = (kglob >> 3) & 3;
            int qa = (2 * qd) & 3, qb = (2 * qd + 1) & 3;
            int jb = (qd & 2) * 2;             // 0 or 4
            bf16* base = dstb + (size_t)kt * 8192 + (size_t)((o >> 4) * 512 + (o & 15) * 8);
            *(uint2*)(base + qa * 128 + jb) = *(const uint2*)&T[row * LT + part * 8];
            *(uint2*)(base + qb * 128 + jb) = *(const uint2*)&T[row * LT + part * 8 + 4];
        }
    }
}

// ---------------------------------------------------------------------------
// K2: fused attention, single-pass online softmax.
// R5: 2 q-groups per wave + 2-way KV-split (flash combine):
//   - block = 512 thr = 8 waves = (4 q-groups x 2 kv-halves); wave owns
//     32 q-rows and 16 of the 32 KV tiles -> each K/V fragment read from
//     LDS feeds 2 MFMAs => LDS-read bytes per q-row HALVED vs R4, while
//     keeping 8 waves/CU (2/SIMD) TLP (R2's mistake fixed).
//   - two independent K+V dbuf streams (one per kv-half), 1 barrier/iter,
//     stage-at-top, 16 iters.
//   - R4's lane-local softmax + permuted-V lane-local PV unchanged.
//   - end merge: m/ps exchange via small LDS array; half-1 waves write
//     alpha-scaled oacc (f32) into the retired K/V LDS area; half-0 waves
//     combine + normalize + write y.
// LDS 133120 B -> 1 block/CU (grid 256). VGPR target ~220 @ lb(512,2).
// ---------------------------------------------------------------------------
__launch_bounds__(512, 2)
__global__ void attn_kernel(const bf16* __restrict__ theta, const bf16* __restrict__ phi_t,
                            const bf16* __restrict__ gt_t, bf16* __restrict__ y) {
    // layout: stream0: K dbuf @0 (32K) | V dbuf @32K (32K)
    //         stream1: K dbuf @64K     | V dbuf @96K
    //         mps @128K (2 KB)
    __shared__ __align__(16) char smem[133120];

    int id = blockIdx.x;                    // 256 blocks
    int b = (id & 7) + 8 * (id >> 6);       // batch: same-batch blocks share XCD class
    int qt = (id >> 3) & 7;                 // 8 tiles of 128 q-rows

    int t = threadIdx.x, lane = t & 63, w = t >> 6;
    int l15 = lane & 15, quad = lane >> 4;
    int qg = w & 3;                          // q-group (32 rows)
    int h  = w >> 2;                         // kv half (tiles h*16 .. h*16+15)
    int hbase = h << 16;                     // byte base of this half's stream

    // per-wave global source pointers for this half's tiles
    const bf16* ph_w = phi_t + (size_t)b * 262144 + (size_t)h * 16 * 8192 + qg * 2048 + lane * 8;
    const bf16* gt_w = gt_t + (size_t)b * 262144 + (size_t)h * 16 * 8192 + qg * 2048 + lane * 8;

    // Q fragments for 2 row-groups (one-time); lane->q, quad->d-chunk
    bf16x8 qf[2][8];
    #pragma unroll
    for (int g = 0; g < 2; ++g) {
        const bf16* qrow = theta + ((size_t)b * NSP + qt * 128 + qg * 32 + g * 16 + l15) * CI;
        #pragma unroll
        for (int kc = 0; kc < 8; ++kc)
            qf[g][kc] = *(const bf16x8*)(qrow + kc * 32 + quad * 8);
    }

    // preload tile 0 of this half's stream
    {
        bf16* kdst = (bf16*)(smem + hbase)         + qg * 2048;
        bf16* vdst = (bf16*)(smem + hbase + 32768) + qg * 2048;
        #pragma unroll
        for (int i = 0; i < 4; ++i) {
            gload_lds16(ph_w + i * 512, kdst + i * 512);
            gload_lds16(gt_w + i * 512, vdst + i * 512);
        }
    }
    __syncthreads();

    f32x4 oacc[2][16] = {};
    float m[2]  = {-1e30f, -1e30f};
    float ps[2] = {0.f, 0.f};

    for (int kt = 0; kt < 16; ++kt) {
        int cur = kt & 1;
        bf16* Kc = (bf16*)(smem + hbase + (cur << 14));
        bf16* Vc = (bf16*)(smem + hbase + 32768 + (cur << 14));

        // (a) async-stage next tile of this half's stream NOW
        if (kt < 15) {
            const bf16* ksrc = ph_w + (size_t)(kt + 1) * 8192;
            const bf16* vsrc = gt_w + (size_t)(kt + 1) * 8192;
            bf16* kdst = (bf16*)(smem + hbase + ((1 - cur) << 14)) + qg * 2048;
            bf16* vdst = (bf16*)(smem + hbase + 32768 + ((1 - cur) << 14)) + qg * 2048;
            #pragma unroll
            for (int i = 0; i < 4; ++i) {
                gload_lds16(ksrc + i * 512, kdst + i * 512);
                gload_lds16(vsrc + i * 512, vdst + i * 512);
            }
        }

        // (b) swapped QK^T for both q-groups: each kf read feeds 2 MFMAs
        f32x4 s0[2] = {}, s1[2] = {};
        __builtin_amdgcn_s_setprio(1);
        #pragma unroll
        for (int kc = 0; kc < 8; ++kc) {
            bf16x8 kf0 = *(const bf16x8*)(Kc + kc * 512 + lane * 8);
            bf16x8 kf1 = *(const bf16x8*)(Kc + 4096 + kc * 512 + lane * 8);
            s0[0] = __builtin_amdgcn_mfma_f32_16x16x32_bf16(kf0, qf[0][kc], s0[0], 0, 0, 0);
            s0[1] = __builtin_amdgcn_mfma_f32_16x16x32_bf16(kf0, qf[1][kc], s0[1], 0, 0, 0);
            s1[0] = __builtin_amdgcn_mfma_f32_16x16x32_bf16(kf1, qf[0][kc], s1[0], 0, 0, 0);
            s1[1] = __builtin_amdgcn_mfma_f32_16x16x32_bf16(kf1, qf[1][kc], s1[1], 0, 0, 0);
        }
        __builtin_amdgcn_s_setprio(0);

        // (c) in-register online softmax per q-group; defer-max THR=8
        float cm[2];
        int flag = 0;
        #pragma unroll
        for (int g = 0; g < 2; ++g) {
            float c = fmaxf(fmaxf(fmaxf(s0[g][0], s0[g][1]), fmaxf(s0[g][2], s0[g][3])),
                            fmaxf(fmaxf(s1[g][0], s1[g][1]), fmaxf(s1[g][2], s1[g][3])));
            c = fmaxf(c, __shfl_xor(c, 16));
            c = fmaxf(c, __shfl_xor(c, 32));
            cm[g] = c;
            flag |= (c > m[g] + 8.0f) ? 1 : 0;
        }
        if (__any(flag)) {
            #pragma unroll
            for (int g = 0; g < 2; ++g) {
                float mn = fmaxf(m[g], cm[g]);
                float alpha = __expf(m[g] - mn);
                m[g] = mn;
                ps[g] *= alpha;
                float a0 = __shfl(alpha, quad * 4 + 0);
                float a1 = __shfl(alpha, quad * 4 + 1);
                float a2 = __shfl(alpha, quad * 4 + 2);
                float a3 = __shfl(alpha, quad * 4 + 3);
                #pragma unroll
                for (int nt = 0; nt < 16; ++nt) {
                    oacc[g][nt][0] *= a0;
                    oacc[g][nt][1] *= a1;
                    oacc[g][nt][2] *= a2;
                    oacc[g][nt][3] *= a3;
                }
            }
        }
        bf16x8 pf[2];
        #pragma unroll
        for (int g = 0; g < 2; ++g) {
            float p0 = __expf(s0[g][0] - m[g]), p1 = __expf(s0[g][1] - m[g]);
            float p2 = __expf(s0[g][2] - m[g]), p3 = __expf(s0[g][3] - m[g]);
            float p4 = __expf(s1[g][0] - m[g]), p5 = __expf(s1[g][1] - m[g]);
            float p6 = __expf(s1[g][2] - m[g]), p7 = __expf(s1[g][3] - m[g]);
            ps[g] += ((p0 + p1) + (p2 + p3)) + ((p4 + p5) + (p6 + p7));
            union { u32 u[4]; bf16x8 v; } cvt;
            cvt.u[0] = pack_bf16(p0, p1);
            cvt.u[1] = pack_bf16(p2, p3);
            cvt.u[2] = pack_bf16(p4, p5);
            cvt.u[3] = pack_bf16(p6, p7);
            pf[g] = cvt.v;
        }

        // (d) PV: each vf read feeds 2 MFMAs (kv-permuted tile, lane-local pf)
        __builtin_amdgcn_s_setprio(1);
        #pragma unroll
        for (int nt = 0; nt < 16; ++nt) {
            bf16x8 vf = *(const bf16x8*)(Vc + nt * 512 + lane * 8);
            oacc[0][nt] = __builtin_amdgcn_mfma_f32_16x16x32_bf16(pf[0], vf, oacc[0][nt], 0, 0, 0);
            oacc[1][nt] = __builtin_amdgcn_mfma_f32_16x16x32_bf16(pf[1], vf, oacc[1][nt], 0, 0, 0);
        }
        __builtin_amdgcn_s_setprio(0);

        // single barrier per iteration: drains DMA + makes staged tiles visible
        __syncthreads();
    }

    // ---- kv-half merge (flash combine) ----
    #pragma unroll
    for (int g = 0; g < 2; ++g) {
        ps[g] += __shfl_xor(ps[g], 16);
        ps[g] += __shfl_xor(ps[g], 32);
    }
    float* mps = (float*)(smem + 131072);   // [8 waves][2 g][16 q][2]
    if (quad == 0) {
        #pragma unroll
        for (int g = 0; g < 2; ++g) {
            float2 v2 = make_float2(m[g], ps[g]);
            *(float2*)&mps[((w * 2 + g) * 16 + l15) * 2] = v2;
        }
    }
    __syncthreads();
    int pw = w ^ 4;
    float ar[2][4], ivr[2][4];
    #pragma unroll
    for (int g = 0; g < 2; ++g) {
        float2 o2 = *(const float2*)&mps[((pw * 2 + g) * 16 + l15) * 2];
        float mf = fmaxf(m[g], o2.x);
        float a  = __expf(m[g] - mf);
        float ao = __expf(o2.x - mf);
        float pd = ps[g] * a + o2.y * ao;
        float iv = 1.0f / pd;
        #pragma unroll
        for (int r = 0; r < 4; ++r) {
            ar[g][r]  = __shfl(a, quad * 4 + r);
            ivr[g][r] = __shfl(iv, quad * 4 + r);
        }
    }
    float* oex = (float*)smem;              // [4 qg][32 q][256 d] f32 = 128 KB
    if (h == 1) {
        #pragma unroll
        for (int g = 0; g < 2; ++g)
            #pragma unroll
            for (int nt = 0; nt < 16; ++nt)
                #pragma unroll
                for (int r = 0; r < 4; ++r)
                    oex[qg * 8192 + (g * 16 + quad * 4 + r) * 256 + nt * 16 + l15] =
                        oacc[g][nt][r] * ar[g][r];
    }
    __syncthreads();
    if (h == 0) {
        #pragma unroll
        for (int g = 0; g < 2; ++g) {
            int nrow = qt * 128 + qg * 32 + g * 16 + quad * 4;
            #pragma unroll
            for (int nt = 0; nt < 16; ++nt) {
                int o = nt * 16 + l15;
                bf16* dst = y + ((((size_t)b * 4 + (o >> 6)) * NSP) + nrow) * 64 + (o & 63);
                #pragma unroll
                for (int r = 0; r < 4; ++r) {
                    float v = oacc[g][nt][r] * ar[g][r] +
                              oex[qg * 8192 + (g * 16 + quad * 4 + r) * 256 + nt * 16 + l15];
                    dst[(size_t)r * 64] = (bf16)(v * ivr[g][r]);
                }
            }
        }
    }
}

// ---------------------------------------------------------------------------
// K3: output GEMM + fused BN stats. LDS cross-wave combine -> 128 atomic
// pairs per block. 4 blocks/CU (LDS 38.9 KB, VGPR 72).
// ---------------------------------------------------------------------------
__launch_bounds__(256, 4)
__global__ void out_gemm(const bf16* __restrict__ y, const bf16* __restrict__ wz,
                         const float* __restrict__ bz, float* __restrict__ wy,
                         float* __restrict__ sums) {
    constexpr int LDA = 72;
    __shared__ __align__(16) bf16 As[128 * LDA];
    __shared__ __align__(16) bf16 Bs[128 * LDA];
    __shared__ float redS[128][2], redS2[128][2];
    int b = blockIdx.z;
    int co0 = blockIdx.y * 128;
    int n0 = blockIdx.x * 128;
    int t = threadIdx.x, lane = t & 63, wid = t >> 6;
    int wm = wid >> 1, wn = wid & 1;
    int l15 = lane & 15, quad = lane >> 4;

    f32x4 acc[4][4] = {};
    for (int kt = 0; kt < 4; ++kt) {
        __syncthreads();
        const bf16* asrc = wz + ((size_t)kt * CH + co0) * 64;
        const bf16* bsrc = y + ((((size_t)b * 4 + kt) * NSP) + n0) * 64;
        for (int s = t; s < 1024; s += 256) {
            int row = s >> 3, c8 = s & 7;
            *(uint4*)&As[row * LDA + c8 * 8] = *(const uint4*)(asrc + (size_t)s * 8);
            *(uint4*)&Bs[row * LDA + c8 * 8] = *(const uint4*)(bsrc + (size_t)s * 8);
        }
        __syncthreads();
        #pragma unroll
        for (int kc = 0; kc < 2; ++kc) {
            bf16x8 af[4], bfv[4];
            #pragma unroll
            for (int i = 0; i < 4; ++i) {
                af[i]  = *(const bf16x8*)&As[(wm * 64 + i * 16 + l15) * LDA + kc * 32 + quad * 8];
                bfv[i] = *(const bf16x8*)&Bs[(wn * 64 + i * 16 + l15) * LDA + kc * 32 + quad * 8];
            }
            #pragma unroll
            for (int i = 0; i < 4; ++i)
                #pragma unroll
                for (int j = 0; j < 4; ++j)
                    acc[i][j] = __builtin_amdgcn_mfma_f32_16x16x32_bf16(af[i], bfv[j], acc[i][j], 0, 0, 0);
        }
    }
    #pragma unroll
    for (int i = 0; i < 4; ++i) {
        int cbase = co0 + wm * 64 + i * 16 + quad * 4;
        #pragma unroll
        for (int r = 0; r < 4; ++r) {
            int c = cbase + r;
            float bv = bz[c];
            float s = 0.f, s2 = 0.f;
            #pragma unroll
            for (int jj = 0; jj < 4; ++jj) {
                int n = n0 + wn * 64 + jj * 16 + l15;
                float v = acc[i][jj][r] + bv;
                wy[((size_t)b * CH + c) * NSP + n] = v;
                s += v; s2 += v * v;
            }
            s  += __shfl_xor(s, 1);  s2 += __shfl_xor(s2, 1);
            s  += __shfl_xor(s, 2);  s2 += __shfl_xor(s2, 2);
            s  += __shfl_xor(s, 4);  s2 += __shfl_xor(s2, 4);
            s  += __shfl_xor(s, 8);  s2 += __shfl_xor(s2, 8);
            if (l15 == 0) {
                int cl = wm * 64 + i * 16 + quad * 4 + r;
                redS[cl][wn]  = s;
                redS2[cl][wn] = s2;
            }
        }
    }
    __syncthreads();
    if (t < 128) {
        atomicAdd(&sums[co0 + t],      redS[t][0] + redS[t][1]);
        atomicAdd(&sums[CH + co0 + t], redS2[t][0] + redS2[t][1]);
    }
}

// ---------------------------------------------------------------------------
// K4: BN normalize + affine + residual, in-place on d_out. float4.
// ---------------------------------------------------------------------------
__global__ void bn_finalize(float* __restrict__ out, const float* __restrict__ x,
                            const float* __restrict__ sums,
                            const float* __restrict__ gamma, const float* __restrict__ beta) {
    size_t idx4 = (size_t)blockIdx.x * 256 + threadIdx.x;
    size_t flat = idx4 * 4;
    int ch = (int)((flat >> 10) & 511);
    float S = sums[ch], S2 = sums[CH + ch];
    const float invcnt = 1.0f / (BATCH * NSP);
    float mean = S * invcnt;
    float var = S2 * invcnt - mean * mean;
    float sc = rsqrtf(var + EPSV) * gamma[ch];
    float bi = beta[ch] - mean * sc;
    float4 wv = *(float4*)(out + flat);
    float4 xv = *(const float4*)(x + flat);
    wv.x = wv.x * sc + bi + xv.x;
    wv.y = wv.y * sc + bi + xv.y;
    wv.z = wv.z * sc + bi + xv.z;
    wv.w = wv.w * sc + bi + xv.w;
    *(float4*)(out + flat) = wv;
}

// ---------------------------------------------------------------------------
extern "C" void kernel_launch(void* const* d_in, const int* in_sizes, int n_in,
                              void* d_out, int out_size, void* d_ws, size_t ws_size,
                              hipStream_t stream) {
    const float* x     = (const float*)d_in[0];
    const float* Wg    = (const float*)d_in[1];
    const float* bg    = (const float*)d_in[2];
    const float* Wt    = (const float*)d_in[3];
    const float* bt    = (const float*)d_in[4];
    const float* Wp    = (const float*)d_in[5];
    const float* bp    = (const float*)d_in[6];
    const float* Wz    = (const float*)d_in[7];
    const float* bz    = (const float*)d_in[8];
    const float* gamma = (const float*)d_in[9];
    const float* beta  = (const float*)d_in[10];
    float* out = (float*)d_out;

    char* ws = (char*)d_ws;
    bf16*  y_t   = (bf16*)(ws);                   // [32][4][1024][64]  16,777,216 B
    bf16*  g_t   = (bf16*)(ws + 16777216);        // blocked V tiles   16,777,216 B
    bf16*  wc    = (bf16*)(ws + 33554432);        // [8][768][64]         786,432 B
    bf16*  wzb   = (bf16*)(ws + 34340864);        // [4][512][64]         262,144 B
    float* sums  = (float*)(ws + 34603008);       // [2][512]               4,096 B

    char* ob = (char*)d_out;                      // d_out as scratch until out_gemm
    bf16* xb    = (bf16*)(ob);                    // [32][8][1024][64] 33,554,432 B
    bf16* theta = (bf16*)(ob + 33554432);         // [32][1024][256]   16,777,216 B
    bf16* phi_t = (bf16*)(ob + 50331648);         // blocked K tiles   16,777,216 B

    prep_weights<<<dim3(2048), dim3(256), 0, stream>>>(Wg, Wt, Wp, Wz, wc, wzb, sums);
    transpose_x<<<dim3(16, 8, 32), dim3(256), 0, stream>>>(x, xb);
    proj_gemm<<<dim3(6, 8, 32), dim3(256), 0, stream>>>(xb, wc, bt, bp, bg, theta, phi_t, g_t);
    attn_kernel<<<dim3(256), dim3(512), 0, stream>>>(theta, phi_t, g_t, y_t);
    out_gemm<<<dim3(8, 4, 32), dim3(256), 0, stream>>>(y_t, wzb, bz, out, sums);
    bn_finalize<<<dim3(16384), dim3(256), 0, stream>>>(out, x, sums, gamma, beta);
}